// Round 7
// baseline (372.502 us; speedup 1.0000x reference)
//
#include <hip/hip_runtime.h>
#include <hip/hip_bf16.h>
#include <math.h>

#define N_NODES 50000
#define N_EDGES 1600000
#define TE 64
#define NB_SCAN 196   // ceil(50000/256)
#define LOG2E 1.44269504088896340736f
#define SC_CHUNK 2048
#define NSEG 8        // dst-range segments (one per XCD)
#define SEG_W (N_NODES / NSEG)   // 6250

// ---------------- node transform ----------------
// h = concat(x, cos(t*omega+phase)) @ W ; also s_src[n,h], s_dst[n,h] (pre-scaled by log2e)
// 256 thr = 16 nodes x 16 threads; each thread computes 4 output cols (float4 acc,
// 4 independent FMA chains). W read directly from global: it is L1/L2-resident
// (48KB, reused by all 3125 blocks) and lanes of a wave dedupe to one 256B
// fetch per k-step. Only the node tile `a` lives in LDS (12.4KB -> high occupancy).
template<int IN_DIM>
__global__ __launch_bounds__(256) void transform_kernel(
    const float* __restrict__ xin, const float* __restrict__ tim,
    const float* __restrict__ omega, const float* __restrict__ phase,
    const float* __restrict__ W, const float* __restrict__ asrc,
    const float* __restrict__ adst,
    float* __restrict__ hfeat, float* __restrict__ s_src, float* __restrict__ s_dst)
{
    constexpr int K = IN_DIM + TE;
    constexpr int KP = K + 1;           // padded row (bank de-conflict)
    constexpr int NPB = 16;             // nodes per block
    __shared__ float a[NPB * KP];
    const int tid = threadIdx.x;
    const int base = blockIdx.x * NPB;  // grid exact: 50000/16 = 3125

    // stage a = concat(x_row, cos(t*omega+phase))
    for (int i = tid; i < NPB * K; i += 256) {
        int nl = i / K, k = i - nl * K;
        int n = base + nl;
        a[nl * KP + k] = (k < IN_DIM)
            ? xin[(size_t)n * IN_DIM + k]
            : cosf(tim[n] * omega[k - IN_DIM] + phase[k - IN_DIM]);
    }
    __syncthreads();

    const int nl = tid >> 4;        // node within block
    const int sl = tid & 15;        // col slot: cols [sl*4, sl*4+4)
    const int n = base + nl;

    float4 acc = make_float4(0.f, 0.f, 0.f, 0.f);
    const float* arow = a + nl * KP;
    const float4* wp = (const float4*)W + sl;   // row k at wp[k*16]
    #pragma unroll 8
    for (int k = 0; k < K; ++k) {
        const float av = arow[k];
        const float4 w4 = wp[k * 16];
        acc.x = fmaf(av, w4.x, acc.x);
        acc.y = fmaf(av, w4.y, acc.y);
        acc.z = fmaf(av, w4.z, acc.z);
        acc.w = fmaf(av, w4.w, acc.w);
    }

    *(float4*)(hfeat + (size_t)n * 64 + sl * 4) = acc;

    const float4 as = *(const float4*)(asrc + sl * 4);
    const float4 ad = *(const float4*)(adst + sl * 4);
    float vs = acc.x * as.x + acc.y * as.y + acc.z * as.z + acc.w * as.w;
    float vd = acc.x * ad.x + acc.y * ad.y + acc.z * ad.z + acc.w * ad.w;
    vs += __shfl_xor(vs, 1, 64); vs += __shfl_xor(vs, 2, 64);
    vd += __shfl_xor(vd, 1, 64); vd += __shfl_xor(vd, 2, 64);
    if ((sl & 3) == 0) {
        s_src[n * 4 + (sl >> 2)] = vs * LOG2E;   // exp2 domain
        s_dst[n * 4 + (sl >> 2)] = vd * LOG2E;
    }
}

// ---------------- CSR build ----------------
// deg count + per-edge rank (order within its dst segment)
__global__ __launch_bounds__(256) void hist_kernel(
    const int* __restrict__ dst, int* __restrict__ deg, int* __restrict__ rank)
{
    int e = blockIdx.x * 256 + threadIdx.x;
    if (e < N_EDGES) rank[e] = atomicAdd(deg + dst[e], 1);
}

__global__ __launch_bounds__(256) void scanA_kernel(
    const int* __restrict__ deg, int* __restrict__ bsum)
{
    __shared__ int sd[4];
    int i = blockIdx.x * 256 + threadIdx.x;
    int v = (i < N_NODES) ? deg[i] : 0;
    #pragma unroll
    for (int off = 32; off; off >>= 1) v += __shfl_xor(v, off, 64);
    if ((threadIdx.x & 63) == 0) sd[threadIdx.x >> 6] = v;
    __syncthreads();
    if (threadIdx.x == 0) bsum[blockIdx.x] = sd[0] + sd[1] + sd[2] + sd[3];
}

__global__ __launch_bounds__(256) void scanB_kernel(int* __restrict__ bsum)
{
    __shared__ int s[256];
    int t = threadIdx.x;
    int v = (t < NB_SCAN) ? bsum[t] : 0;
    s[t] = v;
    __syncthreads();
    #pragma unroll
    for (int off = 1; off < 256; off <<= 1) {
        int u = (t >= off) ? s[t - off] : 0;
        __syncthreads();
        s[t] += u;
        __syncthreads();
    }
    if (t < NB_SCAN) bsum[t] = s[t] - v;   // exclusive
}

__global__ __launch_bounds__(256) void scanC_kernel(
    const int* __restrict__ deg, const int* __restrict__ bsum,
    int* __restrict__ rowptr)
{
    __shared__ int s[256];
    int t = threadIdx.x;
    int i = blockIdx.x * 256 + t;
    int v = (i < N_NODES) ? deg[i] : 0;
    s[t] = v;
    __syncthreads();
    #pragma unroll
    for (int off = 1; off < 256; off <<= 1) {
        int u = (t >= off) ? s[t - off] : 0;
        __syncthreads();
        s[t] += u;
        __syncthreads();
    }
    int excl = s[t] - v + bsum[blockIdx.x];
    if (i < N_NODES) rowptr[i] = excl;
}

// XCD-affine scatter: block tag (blockIdx%8) owns one dst-range segment; the
// 1.6MB epair slice per segment stays resident in the owning XCD's L2, so
// random 8B writes merge into full lines before writeback. Atomic-free (rank
// precomputed in hist). Correct for ANY block->XCD mapping; %8 only buys locality.
__global__ __launch_bounds__(256) void scatter_kernel(
    const int* __restrict__ dst, const int* __restrict__ src,
    const float* __restrict__ ew, const int* __restrict__ rank,
    const int* __restrict__ rowptr, int2* __restrict__ epair)
{
    const int seg = blockIdx.x & (NSEG - 1);
    const int lo = seg * SEG_W, hi = lo + SEG_W;
    const int base = (blockIdx.x >> 3) * SC_CHUNK;
    const int end = (base + SC_CHUNK < N_EDGES) ? base + SC_CHUNK : N_EDGES;
    for (int e = base + threadIdx.x; e < end; e += 256) {
        int d = dst[e];
        if (d >= lo && d < hi) {
            epair[rowptr[d] + rank[e]] = make_int2(src[e], __float_as_int(ew[e]));
        }
    }
}

// ---------------- fused per-dst aggregation ----------------
// one wave per node; 8 subgroups x 8 lanes, 8 edges in flight;
// each lane holds 8 features (two float4): cols [sl*8, sl*8+8).
// no max-subtraction (scores O(1), softmax is shift-invariant); exp2 domain.
template<int FINAL>
__global__ __launch_bounds__(256) void aggregate_kernel(
    const int* __restrict__ rowptr, const int* __restrict__ deg,
    const int2* __restrict__ epair,
    const float* __restrict__ s_src, const float* __restrict__ s_dst,
    const float* __restrict__ hfeat,
    const float* __restrict__ whead, const float* __restrict__ bhead,
    float* __restrict__ outp)
{
    const int n = blockIdx.x * 4 + (threadIdx.x >> 6);
    if (n >= N_NODES) return;
    const int lane = threadIdx.x & 63;
    const int g = lane >> 3;          // subgroup (edge slot 0..7)
    const int sl = lane & 7;          // feature octet
    const int hh = sl >> 1;           // head of my features
    const float sdst = s_dst[n * 4 + hh];
    const int beg = rowptr[n];
    const int cnt = deg[n];

    float den = 0.f;
    float4 a0 = make_float4(0.f, 0.f, 0.f, 0.f);
    float4 a1 = make_float4(0.f, 0.f, 0.f, 0.f);

    int i = g;
    int2 ep = (i < cnt) ? epair[beg + i] : make_int2(0, 0);
    while (i < cnt) {
        const int inext = i + 8;
        int2 epn = (inext < cnt) ? epair[beg + inext] : make_int2(0, 0);
        const int s = ep.x;
        const float w = __int_as_float(ep.y);
        float sc = s_src[(size_t)s * 4 + hh] + sdst;
        sc = fmaxf(sc, 0.2f * sc);                       // leaky relu (log2 domain)
        const float p = __builtin_amdgcn_exp2f(sc) * w;
        const float4* hp = (const float4*)(hfeat + (size_t)s * 64 + sl * 8);
        const float4 h0 = hp[0];
        const float4 h1 = hp[1];
        den += p;
        a0.x = fmaf(p, h0.x, a0.x); a0.y = fmaf(p, h0.y, a0.y);
        a0.z = fmaf(p, h0.z, a0.z); a0.w = fmaf(p, h0.w, a0.w);
        a1.x = fmaf(p, h1.x, a1.x); a1.y = fmaf(p, h1.y, a1.y);
        a1.z = fmaf(p, h1.z, a1.z); a1.w = fmaf(p, h1.w, a1.w);
        ep = epn; i = inext;
    }

    // merge 8 subgroups (lane bits 3,4,5)
    #pragma unroll
    for (int off = 8; off <= 32; off <<= 1) {
        den  += __shfl_xor(den, off, 64);
        a0.x += __shfl_xor(a0.x, off, 64); a0.y += __shfl_xor(a0.y, off, 64);
        a0.z += __shfl_xor(a0.z, off, 64); a0.w += __shfl_xor(a0.w, off, 64);
        a1.x += __shfl_xor(a1.x, off, 64); a1.y += __shfl_xor(a1.y, off, 64);
        a1.z += __shfl_xor(a1.z, off, 64); a1.w += __shfl_xor(a1.w, off, 64);
    }

    const float inv = 1.f / (den + 1e-16f);
    if (!FINAL) {
        if (g == 0) {
            float4 v0, v1;
            v0.x = a0.x * inv; v0.x = v0.x > 0.f ? v0.x : expm1f(v0.x);
            v0.y = a0.y * inv; v0.y = v0.y > 0.f ? v0.y : expm1f(v0.y);
            v0.z = a0.z * inv; v0.z = v0.z > 0.f ? v0.z : expm1f(v0.z);
            v0.w = a0.w * inv; v0.w = v0.w > 0.f ? v0.w : expm1f(v0.w);
            v1.x = a1.x * inv; v1.x = v1.x > 0.f ? v1.x : expm1f(v1.x);
            v1.y = a1.y * inv; v1.y = v1.y > 0.f ? v1.y : expm1f(v1.y);
            v1.z = a1.z * inv; v1.z = v1.z > 0.f ? v1.z : expm1f(v1.z);
            v1.w = a1.w * inv; v1.w = v1.w > 0.f ? v1.w : expm1f(v1.w);
            float4* op = (float4*)(outp + (size_t)n * 64 + sl * 8);
            op[0] = v0; op[1] = v1;
        }
    } else {
        const float4* wp = (const float4*)(whead + sl * 8);
        const float4 w0 = wp[0], w1 = wp[1];
        float v = (a0.x * w0.x + a0.y * w0.y + a0.z * w0.z + a0.w * w0.w
                 + a1.x * w1.x + a1.y * w1.y + a1.z * w1.z + a1.w * w1.w) * inv;
        #pragma unroll
        for (int off = 1; off <= 4; off <<= 1) v += __shfl_xor(v, off, 64);
        if (lane == 0) outp[n] = v + bhead[0];
    }
}

extern "C" void kernel_launch(void* const* d_in, const int* in_sizes, int n_in,
                              void* d_out, int out_size, void* d_ws, size_t ws_size,
                              hipStream_t stream) {
    const float* x      = (const float*)d_in[0];
    const int*   eidx   = (const int*)d_in[1];
    const float* ew     = (const float*)d_in[2];
    const float* tim    = (const float*)d_in[3];
    const float* omega0 = (const float*)d_in[4];
    const float* phase0 = (const float*)d_in[5];
    const float* W0     = (const float*)d_in[6];
    const float* asrc0  = (const float*)d_in[7];
    const float* adst0  = (const float*)d_in[8];
    const float* omega1 = (const float*)d_in[9];
    const float* phase1 = (const float*)d_in[10];
    const float* W1     = (const float*)d_in[11];
    const float* asrc1  = (const float*)d_in[12];
    const float* adst1  = (const float*)d_in[13];
    const float* Whead  = (const float*)d_in[14];
    const float* bhead  = (const float*)d_in[15];
    float* out = (float*)d_out;

    const int* src = eidx;
    const int* dst = eidx + N_EDGES;

    float* ws = (float*)d_ws;
    float* hfeat = ws;                               // N*64
    float* x1    = hfeat + (size_t)N_NODES * 64;     // N*64
    float* s_src = x1    + (size_t)N_NODES * 64;     // N*4
    float* s_dst = s_src + (size_t)N_NODES * 4;      // N*4
    int2* epair  = (int2*)(s_dst + (size_t)N_NODES * 4);   // E (8B each)
    int* deg     = (int*)(epair + (size_t)N_EDGES);  // N
    int* rowptr  = deg + N_NODES;                    // N
    int* bsum    = rowptr + N_NODES;                 // 256
    int* rank    = (int*)x1;                         // E ints, aliases x1 (dead until aggregate<0>)

    const int tf_grid   = N_NODES / 16;              // 3125, exact
    const int edge_grid = (N_EDGES + 255) / 256;
    const int agg_grid  = (N_NODES + 3) / 4;
    const int sc_grid   = ((N_EDGES + SC_CHUNK - 1) / SC_CHUNK) * NSEG;

    // ---- CSR build (edge structure shared by both layers) ----
    hipMemsetAsync(deg, 0, N_NODES * sizeof(int), stream);
    hist_kernel<<<edge_grid, 256, 0, stream>>>(dst, deg, rank);
    scanA_kernel<<<NB_SCAN, 256, 0, stream>>>(deg, bsum);
    scanB_kernel<<<1, 256, 0, stream>>>(bsum);
    scanC_kernel<<<NB_SCAN, 256, 0, stream>>>(deg, bsum, rowptr);
    scatter_kernel<<<sc_grid, 256, 0, stream>>>(dst, src, ew, rank, rowptr, epair);

    // ---- layer 0 ----
    transform_kernel<128><<<tf_grid, 256, 0, stream>>>(
        x, tim, omega0, phase0, W0, asrc0, adst0, hfeat, s_src, s_dst);
    aggregate_kernel<0><<<agg_grid, 256, 0, stream>>>(
        rowptr, deg, epair, s_src, s_dst, hfeat, Whead, bhead, x1);

    // ---- layer 1 (+ fused linear head) ----
    transform_kernel<64><<<tf_grid, 256, 0, stream>>>(
        x1, tim, omega1, phase1, W1, asrc1, adst1, hfeat, s_src, s_dst);
    aggregate_kernel<1><<<agg_grid, 256, 0, stream>>>(
        rowptr, deg, epair, s_src, s_dst, hfeat, Whead, bhead, out);
}

// Round 8
// 301.609 us; speedup vs baseline: 1.2351x; 1.2351x over previous
//
#include <hip/hip_runtime.h>
#include <hip/hip_bf16.h>
#include <math.h>

#define N_NODES 50000
#define N_EDGES 1600000
#define TE 64
#define NB_SCAN 196   // ceil(50000/256)
#define LOG2E 1.44269504088896340736f
#define SC_CHUNK 2048
#define NSEG 8        // dst-range segments (one per XCD)
#define SEG_W (N_NODES / NSEG)   // 6250

// ---------------- node transform ----------------
// h = concat(x, cos(t*omega+phase)) @ W ; also s_src[n,h], s_dst[n,h] (pre-scaled
// by log2e). Register-tiled GEMM: block = 64 nodes x 64 cols, 256 thr = 16x16,
// thread tile 4 nodes x 4 cols (16 FMA per {1 aS b128 + 1 wS b128} read pair).
// K staged in 32-chunks; aS transposed [k][node] (row 68 -> 16B aligned, 2-way
// bank alias only); wS [k][64]. IN_DIM % 32 == 0 so chunks are purely-xin or
// purely-cos.
template<int IN_DIM>
__global__ __launch_bounds__(256) void transform_kernel(
    const float* __restrict__ xin, const float* __restrict__ tim,
    const float* __restrict__ omega, const float* __restrict__ phase,
    const float* __restrict__ W, const float* __restrict__ asrc,
    const float* __restrict__ adst,
    float* __restrict__ hfeat, float* __restrict__ s_src, float* __restrict__ s_dst)
{
    constexpr int K = IN_DIM + TE;
    constexpr int KC = 32;             // k-chunk
    constexpr int NCH = K / KC;
    constexpr int BN = 64;             // nodes per block
    __shared__ float aS[KC][68];       // transposed a-chunk (padded row: 272B)
    __shared__ float wS[KC][64];
    __shared__ float tS[BN];

    const int tid = threadIdx.x;
    const int base = blockIdx.x * BN;

    if (tid < BN) {
        int n = base + tid;
        tS[tid] = (n < N_NODES) ? tim[n] : 0.f;
    }

    const int ty = tid >> 4;           // node quad: nodes ty*4 .. ty*4+3
    const int tx = tid & 15;           // col slot: cols tx*4 .. tx*4+3

    float acc[4][4] = {};

    for (int ch = 0; ch < NCH; ++ch) {
        const int kg0 = ch * KC;
        __syncthreads();               // previous chunk fully consumed

        // stage W chunk: 32x64 floats = 512 float4, 2 per thread (coalesced)
        #pragma unroll
        for (int j = 0; j < 2; ++j) {
            int idx = tid + j * 256;                    // float4 index
            int kk = idx >> 4, c4 = idx & 15;
            *(float4*)&wS[kk][c4 * 4] =
                ((const float4*)(W + (size_t)(kg0 + kk) * 64))[c4];
        }

        // stage a chunk (transposed)
        if (kg0 < IN_DIM) {
            // from xin: idx -> node = idx>>3, kquad = idx&7 (float4 coalesced)
            #pragma unroll
            for (int j = 0; j < 2; ++j) {
                int idx = tid + j * 256;
                int nl = idx >> 3, kk = (idx & 7) * 4;
                int n = base + nl;
                float4 v = (n < N_NODES)
                    ? ((const float4*)(xin + (size_t)n * IN_DIM + kg0))[idx & 7]
                    : make_float4(0.f, 0.f, 0.f, 0.f);
                aS[kk + 0][nl] = v.x;
                aS[kk + 1][nl] = v.y;
                aS[kk + 2][nl] = v.z;
                aS[kk + 3][nl] = v.w;
            }
        } else {
            // cos part: idx -> kk = idx>>6 (wave-uniform), node = idx&63
            #pragma unroll
            for (int j = 0; j < 8; ++j) {
                int idx = tid + j * 256;
                int kk = idx >> 6, nl = idx & 63;
                int kg = kg0 + kk - IN_DIM;
                aS[kk][nl] = cosf(tS[nl] * omega[kg] + phase[kg]);
            }
        }
        __syncthreads();

        #pragma unroll
        for (int k = 0; k < KC; ++k) {
            const float4 av = *(const float4*)&aS[k][ty * 4];
            const float4 wv = *(const float4*)&wS[k][tx * 4];
            acc[0][0] = fmaf(av.x, wv.x, acc[0][0]);
            acc[0][1] = fmaf(av.x, wv.y, acc[0][1]);
            acc[0][2] = fmaf(av.x, wv.z, acc[0][2]);
            acc[0][3] = fmaf(av.x, wv.w, acc[0][3]);
            acc[1][0] = fmaf(av.y, wv.x, acc[1][0]);
            acc[1][1] = fmaf(av.y, wv.y, acc[1][1]);
            acc[1][2] = fmaf(av.y, wv.z, acc[1][2]);
            acc[1][3] = fmaf(av.y, wv.w, acc[1][3]);
            acc[2][0] = fmaf(av.z, wv.x, acc[2][0]);
            acc[2][1] = fmaf(av.z, wv.y, acc[2][1]);
            acc[2][2] = fmaf(av.z, wv.z, acc[2][2]);
            acc[2][3] = fmaf(av.z, wv.w, acc[2][3]);
            acc[3][0] = fmaf(av.w, wv.x, acc[3][0]);
            acc[3][1] = fmaf(av.w, wv.y, acc[3][1]);
            acc[3][2] = fmaf(av.w, wv.z, acc[3][2]);
            acc[3][3] = fmaf(av.w, wv.w, acc[3][3]);
        }
    }

    // epilogue: hfeat stores + per-head scores
    const float4 as = ((const float4*)asrc)[tx];
    const float4 ad = ((const float4*)adst)[tx];
    #pragma unroll
    for (int j = 0; j < 4; ++j) {
        const int n = base + ty * 4 + j;
        if (n < N_NODES) {
            *(float4*)(hfeat + (size_t)n * 64 + tx * 4) =
                make_float4(acc[j][0], acc[j][1], acc[j][2], acc[j][3]);
        }
        float vs = acc[j][0] * as.x + acc[j][1] * as.y
                 + acc[j][2] * as.z + acc[j][3] * as.w;
        float vd = acc[j][0] * ad.x + acc[j][1] * ad.y
                 + acc[j][2] * ad.z + acc[j][3] * ad.w;
        vs += __shfl_xor(vs, 1, 64); vs += __shfl_xor(vs, 2, 64);
        vd += __shfl_xor(vd, 1, 64); vd += __shfl_xor(vd, 2, 64);
        if ((tx & 3) == 0 && n < N_NODES) {
            s_src[n * 4 + (tx >> 2)] = vs * LOG2E;   // exp2 domain
            s_dst[n * 4 + (tx >> 2)] = vd * LOG2E;
        }
    }
}

// ---------------- CSR build ----------------
// deg count + per-edge rank (order within its dst segment)
__global__ __launch_bounds__(256) void hist_kernel(
    const int* __restrict__ dst, int* __restrict__ deg, int* __restrict__ rank)
{
    int e = blockIdx.x * 256 + threadIdx.x;
    if (e < N_EDGES) rank[e] = atomicAdd(deg + dst[e], 1);
}

__global__ __launch_bounds__(256) void scanA_kernel(
    const int* __restrict__ deg, int* __restrict__ bsum)
{
    __shared__ int sd[4];
    int i = blockIdx.x * 256 + threadIdx.x;
    int v = (i < N_NODES) ? deg[i] : 0;
    #pragma unroll
    for (int off = 32; off; off >>= 1) v += __shfl_xor(v, off, 64);
    if ((threadIdx.x & 63) == 0) sd[threadIdx.x >> 6] = v;
    __syncthreads();
    if (threadIdx.x == 0) bsum[blockIdx.x] = sd[0] + sd[1] + sd[2] + sd[3];
}

__global__ __launch_bounds__(256) void scanB_kernel(int* __restrict__ bsum)
{
    __shared__ int s[256];
    int t = threadIdx.x;
    int v = (t < NB_SCAN) ? bsum[t] : 0;
    s[t] = v;
    __syncthreads();
    #pragma unroll
    for (int off = 1; off < 256; off <<= 1) {
        int u = (t >= off) ? s[t - off] : 0;
        __syncthreads();
        s[t] += u;
        __syncthreads();
    }
    if (t < NB_SCAN) bsum[t] = s[t] - v;   // exclusive
}

__global__ __launch_bounds__(256) void scanC_kernel(
    const int* __restrict__ deg, const int* __restrict__ bsum,
    int* __restrict__ rowptr)
{
    __shared__ int s[256];
    int t = threadIdx.x;
    int i = blockIdx.x * 256 + t;
    int v = (i < N_NODES) ? deg[i] : 0;
    s[t] = v;
    __syncthreads();
    #pragma unroll
    for (int off = 1; off < 256; off <<= 1) {
        int u = (t >= off) ? s[t - off] : 0;
        __syncthreads();
        s[t] += u;
        __syncthreads();
    }
    int excl = s[t] - v + bsum[blockIdx.x];
    if (i < N_NODES) rowptr[i] = excl;
}

// XCD-affine scatter: block tag (blockIdx%8) owns one dst-range segment; the
// 1.6MB epair slice per segment stays resident in the owning XCD's L2, so
// random 8B writes merge into full lines before writeback. Atomic-free (rank
// precomputed in hist). Correct for ANY block->XCD mapping; %8 only buys locality.
__global__ __launch_bounds__(256) void scatter_kernel(
    const int* __restrict__ dst, const int* __restrict__ src,
    const float* __restrict__ ew, const int* __restrict__ rank,
    const int* __restrict__ rowptr, int2* __restrict__ epair)
{
    const int seg = blockIdx.x & (NSEG - 1);
    const int lo = seg * SEG_W, hi = lo + SEG_W;
    const int base = (blockIdx.x >> 3) * SC_CHUNK;
    const int end = (base + SC_CHUNK < N_EDGES) ? base + SC_CHUNK : N_EDGES;
    for (int e = base + threadIdx.x; e < end; e += 256) {
        int d = dst[e];
        if (d >= lo && d < hi) {
            epair[rowptr[d] + rank[e]] = make_int2(src[e], __float_as_int(ew[e]));
        }
    }
}

// ---------------- fused per-dst aggregation ----------------
// one wave per node; 8 subgroups x 8 lanes, 8 edges in flight;
// each lane holds 8 features (two float4): cols [sl*8, sl*8+8).
// no max-subtraction (scores O(1), softmax is shift-invariant); exp2 domain.
template<int FINAL>
__global__ __launch_bounds__(256) void aggregate_kernel(
    const int* __restrict__ rowptr, const int* __restrict__ deg,
    const int2* __restrict__ epair,
    const float* __restrict__ s_src, const float* __restrict__ s_dst,
    const float* __restrict__ hfeat,
    const float* __restrict__ whead, const float* __restrict__ bhead,
    float* __restrict__ outp)
{
    const int n = blockIdx.x * 4 + (threadIdx.x >> 6);
    if (n >= N_NODES) return;
    const int lane = threadIdx.x & 63;
    const int g = lane >> 3;          // subgroup (edge slot 0..7)
    const int sl = lane & 7;          // feature octet
    const int hh = sl >> 1;           // head of my features
    const float sdst = s_dst[n * 4 + hh];
    const int beg = rowptr[n];
    const int cnt = deg[n];

    float den = 0.f;
    float4 a0 = make_float4(0.f, 0.f, 0.f, 0.f);
    float4 a1 = make_float4(0.f, 0.f, 0.f, 0.f);

    int i = g;
    int2 ep = (i < cnt) ? epair[beg + i] : make_int2(0, 0);
    while (i < cnt) {
        const int inext = i + 8;
        int2 epn = (inext < cnt) ? epair[beg + inext] : make_int2(0, 0);
        const int s = ep.x;
        const float w = __int_as_float(ep.y);
        float sc = s_src[(size_t)s * 4 + hh] + sdst;
        sc = fmaxf(sc, 0.2f * sc);                       // leaky relu (log2 domain)
        const float p = __builtin_amdgcn_exp2f(sc) * w;
        const float4* hp = (const float4*)(hfeat + (size_t)s * 64 + sl * 8);
        const float4 h0 = hp[0];
        const float4 h1 = hp[1];
        den += p;
        a0.x = fmaf(p, h0.x, a0.x); a0.y = fmaf(p, h0.y, a0.y);
        a0.z = fmaf(p, h0.z, a0.z); a0.w = fmaf(p, h0.w, a0.w);
        a1.x = fmaf(p, h1.x, a1.x); a1.y = fmaf(p, h1.y, a1.y);
        a1.z = fmaf(p, h1.z, a1.z); a1.w = fmaf(p, h1.w, a1.w);
        ep = epn; i = inext;
    }

    // merge 8 subgroups (lane bits 3,4,5)
    #pragma unroll
    for (int off = 8; off <= 32; off <<= 1) {
        den  += __shfl_xor(den, off, 64);
        a0.x += __shfl_xor(a0.x, off, 64); a0.y += __shfl_xor(a0.y, off, 64);
        a0.z += __shfl_xor(a0.z, off, 64); a0.w += __shfl_xor(a0.w, off, 64);
        a1.x += __shfl_xor(a1.x, off, 64); a1.y += __shfl_xor(a1.y, off, 64);
        a1.z += __shfl_xor(a1.z, off, 64); a1.w += __shfl_xor(a1.w, off, 64);
    }

    const float inv = 1.f / (den + 1e-16f);
    if (!FINAL) {
        if (g == 0) {
            float4 v0, v1;
            v0.x = a0.x * inv; v0.x = v0.x > 0.f ? v0.x : expm1f(v0.x);
            v0.y = a0.y * inv; v0.y = v0.y > 0.f ? v0.y : expm1f(v0.y);
            v0.z = a0.z * inv; v0.z = v0.z > 0.f ? v0.z : expm1f(v0.z);
            v0.w = a0.w * inv; v0.w = v0.w > 0.f ? v0.w : expm1f(v0.w);
            v1.x = a1.x * inv; v1.x = v1.x > 0.f ? v1.x : expm1f(v1.x);
            v1.y = a1.y * inv; v1.y = v1.y > 0.f ? v1.y : expm1f(v1.y);
            v1.z = a1.z * inv; v1.z = v1.z > 0.f ? v1.z : expm1f(v1.z);
            v1.w = a1.w * inv; v1.w = v1.w > 0.f ? v1.w : expm1f(v1.w);
            float4* op = (float4*)(outp + (size_t)n * 64 + sl * 8);
            op[0] = v0; op[1] = v1;
        }
    } else {
        const float4* wp = (const float4*)(whead + sl * 8);
        const float4 w0 = wp[0], w1 = wp[1];
        float v = (a0.x * w0.x + a0.y * w0.y + a0.z * w0.z + a0.w * w0.w
                 + a1.x * w1.x + a1.y * w1.y + a1.z * w1.z + a1.w * w1.w) * inv;
        #pragma unroll
        for (int off = 1; off <= 4; off <<= 1) v += __shfl_xor(v, off, 64);
        if (lane == 0) outp[n] = v + bhead[0];
    }
}

extern "C" void kernel_launch(void* const* d_in, const int* in_sizes, int n_in,
                              void* d_out, int out_size, void* d_ws, size_t ws_size,
                              hipStream_t stream) {
    const float* x      = (const float*)d_in[0];
    const int*   eidx   = (const int*)d_in[1];
    const float* ew     = (const float*)d_in[2];
    const float* tim    = (const float*)d_in[3];
    const float* omega0 = (const float*)d_in[4];
    const float* phase0 = (const float*)d_in[5];
    const float* W0     = (const float*)d_in[6];
    const float* asrc0  = (const float*)d_in[7];
    const float* adst0  = (const float*)d_in[8];
    const float* omega1 = (const float*)d_in[9];
    const float* phase1 = (const float*)d_in[10];
    const float* W1     = (const float*)d_in[11];
    const float* asrc1  = (const float*)d_in[12];
    const float* adst1  = (const float*)d_in[13];
    const float* Whead  = (const float*)d_in[14];
    const float* bhead  = (const float*)d_in[15];
    float* out = (float*)d_out;

    const int* src = eidx;
    const int* dst = eidx + N_EDGES;

    float* ws = (float*)d_ws;
    float* hfeat = ws;                               // N*64
    float* x1    = hfeat + (size_t)N_NODES * 64;     // N*64
    float* s_src = x1    + (size_t)N_NODES * 64;     // N*4
    float* s_dst = s_src + (size_t)N_NODES * 4;      // N*4
    int2* epair  = (int2*)(s_dst + (size_t)N_NODES * 4);   // E (8B each)
    int* deg     = (int*)(epair + (size_t)N_EDGES);  // N
    int* rowptr  = deg + N_NODES;                    // N
    int* bsum    = rowptr + N_NODES;                 // 256
    int* rank    = (int*)x1;                         // E ints, aliases x1 (dead until aggregate<0>)

    const int tf_grid   = (N_NODES + 63) / 64;       // 782
    const int edge_grid = (N_EDGES + 255) / 256;
    const int agg_grid  = (N_NODES + 3) / 4;
    const int sc_grid   = ((N_EDGES + SC_CHUNK - 1) / SC_CHUNK) * NSEG;

    // ---- CSR build (edge structure shared by both layers) ----
    hipMemsetAsync(deg, 0, N_NODES * sizeof(int), stream);
    hist_kernel<<<edge_grid, 256, 0, stream>>>(dst, deg, rank);
    scanA_kernel<<<NB_SCAN, 256, 0, stream>>>(deg, bsum);
    scanB_kernel<<<1, 256, 0, stream>>>(bsum);
    scanC_kernel<<<NB_SCAN, 256, 0, stream>>>(deg, bsum, rowptr);
    scatter_kernel<<<sc_grid, 256, 0, stream>>>(dst, src, ew, rank, rowptr, epair);

    // ---- layer 0 ----
    transform_kernel<128><<<tf_grid, 256, 0, stream>>>(
        x, tim, omega0, phase0, W0, asrc0, adst0, hfeat, s_src, s_dst);
    aggregate_kernel<0><<<agg_grid, 256, 0, stream>>>(
        rowptr, deg, epair, s_src, s_dst, hfeat, Whead, bhead, x1);

    // ---- layer 1 (+ fused linear head) ----
    transform_kernel<64><<<tf_grid, 256, 0, stream>>>(
        x1, tim, omega1, phase1, W1, asrc1, adst1, hfeat, s_src, s_dst);
    aggregate_kernel<1><<<agg_grid, 256, 0, stream>>>(
        rowptr, deg, epair, s_src, s_dst, hfeat, Whead, bhead, out);
}

// Round 9
// 301.393 us; speedup vs baseline: 1.2359x; 1.0007x over previous
//
#include <hip/hip_runtime.h>
#include <hip/hip_bf16.h>
#include <math.h>

#define N_NODES 50000
#define N_EDGES 1600000
#define TE 64
#define NB_SCAN 196   // ceil(50000/256)
#define LOG2E 1.44269504088896340736f
#define SC_CHUNK 2048
#define NSEG 8        // dst-range segments (one per XCD)
#define SEG_W (N_NODES / NSEG)   // 6250

// ---------------- node transform ----------------
// h = concat(x, cos(t*omega+phase)) @ W ; also s_src[n,h], s_dst[n,h] (pre-scaled
// by log2e). Register-tiled GEMM: block = 64 nodes x 64 cols, 256 thr = 16x16,
// thread tile 4 nodes x 4 cols (16 FMA per {1 aS b128 + 1 wS b128} read pair).
// K staged in 32-chunks; aS transposed [k][node] (row 68 -> 16B aligned, 2-way
// bank alias only); wS [k][64]. IN_DIM % 32 == 0 so chunks are purely-xin or
// purely-cos.
template<int IN_DIM>
__global__ __launch_bounds__(256) void transform_kernel(
    const float* __restrict__ xin, const float* __restrict__ tim,
    const float* __restrict__ omega, const float* __restrict__ phase,
    const float* __restrict__ W, const float* __restrict__ asrc,
    const float* __restrict__ adst,
    float* __restrict__ hfeat, float* __restrict__ s_src, float* __restrict__ s_dst)
{
    constexpr int K = IN_DIM + TE;
    constexpr int KC = 32;             // k-chunk
    constexpr int NCH = K / KC;
    constexpr int BN = 64;             // nodes per block
    __shared__ float aS[KC][68];       // transposed a-chunk (padded row: 272B)
    __shared__ float wS[KC][64];
    __shared__ float tS[BN];

    const int tid = threadIdx.x;
    const int base = blockIdx.x * BN;

    if (tid < BN) {
        int n = base + tid;
        tS[tid] = (n < N_NODES) ? tim[n] : 0.f;
    }

    const int ty = tid >> 4;           // node quad: nodes ty*4 .. ty*4+3
    const int tx = tid & 15;           // col slot: cols tx*4 .. tx*4+3

    float acc[4][4] = {};

    for (int ch = 0; ch < NCH; ++ch) {
        const int kg0 = ch * KC;
        __syncthreads();               // previous chunk fully consumed

        // stage W chunk: 32x64 floats = 512 float4, 2 per thread (coalesced)
        #pragma unroll
        for (int j = 0; j < 2; ++j) {
            int idx = tid + j * 256;                    // float4 index
            int kk = idx >> 4, c4 = idx & 15;
            *(float4*)&wS[kk][c4 * 4] =
                ((const float4*)(W + (size_t)(kg0 + kk) * 64))[c4];
        }

        // stage a chunk (transposed)
        if (kg0 < IN_DIM) {
            // from xin: idx -> node = idx>>3, kquad = idx&7 (float4 coalesced)
            #pragma unroll
            for (int j = 0; j < 2; ++j) {
                int idx = tid + j * 256;
                int nl = idx >> 3, kk = (idx & 7) * 4;
                int n = base + nl;
                float4 v = (n < N_NODES)
                    ? ((const float4*)(xin + (size_t)n * IN_DIM + kg0))[idx & 7]
                    : make_float4(0.f, 0.f, 0.f, 0.f);
                aS[kk + 0][nl] = v.x;
                aS[kk + 1][nl] = v.y;
                aS[kk + 2][nl] = v.z;
                aS[kk + 3][nl] = v.w;
            }
        } else {
            // cos part: idx -> kk = idx>>6 (wave-uniform), node = idx&63
            #pragma unroll
            for (int j = 0; j < 8; ++j) {
                int idx = tid + j * 256;
                int kk = idx >> 6, nl = idx & 63;
                int kg = kg0 + kk - IN_DIM;
                aS[kk][nl] = cosf(tS[nl] * omega[kg] + phase[kg]);
            }
        }
        __syncthreads();

        #pragma unroll
        for (int k = 0; k < KC; ++k) {
            const float4 av = *(const float4*)&aS[k][ty * 4];
            const float4 wv = *(const float4*)&wS[k][tx * 4];
            acc[0][0] = fmaf(av.x, wv.x, acc[0][0]);
            acc[0][1] = fmaf(av.x, wv.y, acc[0][1]);
            acc[0][2] = fmaf(av.x, wv.z, acc[0][2]);
            acc[0][3] = fmaf(av.x, wv.w, acc[0][3]);
            acc[1][0] = fmaf(av.y, wv.x, acc[1][0]);
            acc[1][1] = fmaf(av.y, wv.y, acc[1][1]);
            acc[1][2] = fmaf(av.y, wv.z, acc[1][2]);
            acc[1][3] = fmaf(av.y, wv.w, acc[1][3]);
            acc[2][0] = fmaf(av.z, wv.x, acc[2][0]);
            acc[2][1] = fmaf(av.z, wv.y, acc[2][1]);
            acc[2][2] = fmaf(av.z, wv.z, acc[2][2]);
            acc[2][3] = fmaf(av.z, wv.w, acc[2][3]);
            acc[3][0] = fmaf(av.w, wv.x, acc[3][0]);
            acc[3][1] = fmaf(av.w, wv.y, acc[3][1]);
            acc[3][2] = fmaf(av.w, wv.z, acc[3][2]);
            acc[3][3] = fmaf(av.w, wv.w, acc[3][3]);
        }
    }

    // epilogue: hfeat stores + per-head scores
    const float4 as = ((const float4*)asrc)[tx];
    const float4 ad = ((const float4*)adst)[tx];
    #pragma unroll
    for (int j = 0; j < 4; ++j) {
        const int n = base + ty * 4 + j;
        if (n < N_NODES) {
            *(float4*)(hfeat + (size_t)n * 64 + tx * 4) =
                make_float4(acc[j][0], acc[j][1], acc[j][2], acc[j][3]);
        }
        float vs = acc[j][0] * as.x + acc[j][1] * as.y
                 + acc[j][2] * as.z + acc[j][3] * as.w;
        float vd = acc[j][0] * ad.x + acc[j][1] * ad.y
                 + acc[j][2] * ad.z + acc[j][3] * ad.w;
        vs += __shfl_xor(vs, 1, 64); vs += __shfl_xor(vs, 2, 64);
        vd += __shfl_xor(vd, 1, 64); vd += __shfl_xor(vd, 2, 64);
        if ((tx & 3) == 0 && n < N_NODES) {
            s_src[n * 4 + (tx >> 2)] = vs * LOG2E;   // exp2 domain
            s_dst[n * 4 + (tx >> 2)] = vd * LOG2E;
        }
    }
}

// ---------------- CSR build ----------------
// XCD-affine hist: block tag (blockIdx%8) owns one dst-range segment; atomics
// to deg[lo,hi) issue (heuristically) from one XCD, so the counter lines stay
// in that XCD's L2 instead of ping-ponging through the coherence point.
// rank[e] = arrival order within dst (any unique order is valid).
// Correct for ANY block->XCD mapping; %8 only buys locality.
__global__ __launch_bounds__(256) void hist_kernel(
    const int* __restrict__ dst, int* __restrict__ deg, int* __restrict__ rank)
{
    const int seg = blockIdx.x & (NSEG - 1);
    const int lo = seg * SEG_W, hi = lo + SEG_W;
    const int base = (blockIdx.x >> 3) * SC_CHUNK;
    const int end = (base + SC_CHUNK < N_EDGES) ? base + SC_CHUNK : N_EDGES;
    for (int e = base + threadIdx.x; e < end; e += 256) {
        int d = dst[e];
        if (d >= lo && d < hi)
            rank[e] = atomicAdd(deg + d, 1);
    }
}

__global__ __launch_bounds__(256) void scanA_kernel(
    const int* __restrict__ deg, int* __restrict__ bsum)
{
    __shared__ int sd[4];
    int i = blockIdx.x * 256 + threadIdx.x;
    int v = (i < N_NODES) ? deg[i] : 0;
    #pragma unroll
    for (int off = 32; off; off >>= 1) v += __shfl_xor(v, off, 64);
    if ((threadIdx.x & 63) == 0) sd[threadIdx.x >> 6] = v;
    __syncthreads();
    if (threadIdx.x == 0) bsum[blockIdx.x] = sd[0] + sd[1] + sd[2] + sd[3];
}

__global__ __launch_bounds__(256) void scanB_kernel(int* __restrict__ bsum)
{
    __shared__ int s[256];
    int t = threadIdx.x;
    int v = (t < NB_SCAN) ? bsum[t] : 0;
    s[t] = v;
    __syncthreads();
    #pragma unroll
    for (int off = 1; off < 256; off <<= 1) {
        int u = (t >= off) ? s[t - off] : 0;
        __syncthreads();
        s[t] += u;
        __syncthreads();
    }
    if (t < NB_SCAN) bsum[t] = s[t] - v;   // exclusive
}

__global__ __launch_bounds__(256) void scanC_kernel(
    const int* __restrict__ deg, const int* __restrict__ bsum,
    int* __restrict__ rowptr)
{
    __shared__ int s[256];
    int t = threadIdx.x;
    int i = blockIdx.x * 256 + t;
    int v = (i < N_NODES) ? deg[i] : 0;
    s[t] = v;
    __syncthreads();
    #pragma unroll
    for (int off = 1; off < 256; off <<= 1) {
        int u = (t >= off) ? s[t - off] : 0;
        __syncthreads();
        s[t] += u;
        __syncthreads();
    }
    int excl = s[t] - v + bsum[blockIdx.x];
    if (i < N_NODES) rowptr[i] = excl;
}

// XCD-affine scatter: block tag (blockIdx%8) owns one dst-range segment; the
// 1.6MB epair slice per segment stays resident in the owning XCD's L2, so
// random 8B writes merge into full lines before writeback. Atomic-free (rank
// precomputed in hist). Correct for ANY block->XCD mapping; %8 only buys locality.
__global__ __launch_bounds__(256) void scatter_kernel(
    const int* __restrict__ dst, const int* __restrict__ src,
    const float* __restrict__ ew, const int* __restrict__ rank,
    const int* __restrict__ rowptr, int2* __restrict__ epair)
{
    const int seg = blockIdx.x & (NSEG - 1);
    const int lo = seg * SEG_W, hi = lo + SEG_W;
    const int base = (blockIdx.x >> 3) * SC_CHUNK;
    const int end = (base + SC_CHUNK < N_EDGES) ? base + SC_CHUNK : N_EDGES;
    for (int e = base + threadIdx.x; e < end; e += 256) {
        int d = dst[e];
        if (d >= lo && d < hi) {
            epair[rowptr[d] + rank[e]] = make_int2(src[e], __float_as_int(ew[e]));
        }
    }
}

// ---------------- fused per-dst aggregation ----------------
// one wave per node; 8 subgroups x 8 lanes, 8 edges in flight;
// each lane holds 8 features (two float4): cols [sl*8, sl*8+8).
// no max-subtraction (scores O(1), softmax is shift-invariant); exp2 domain.
template<int FINAL>
__global__ __launch_bounds__(256) void aggregate_kernel(
    const int* __restrict__ rowptr, const int* __restrict__ deg,
    const int2* __restrict__ epair,
    const float* __restrict__ s_src, const float* __restrict__ s_dst,
    const float* __restrict__ hfeat,
    const float* __restrict__ whead, const float* __restrict__ bhead,
    float* __restrict__ outp)
{
    const int n = blockIdx.x * 4 + (threadIdx.x >> 6);
    if (n >= N_NODES) return;
    const int lane = threadIdx.x & 63;
    const int g = lane >> 3;          // subgroup (edge slot 0..7)
    const int sl = lane & 7;          // feature octet
    const int hh = sl >> 1;           // head of my features
    const float sdst = s_dst[n * 4 + hh];
    const int beg = rowptr[n];
    const int cnt = deg[n];

    float den = 0.f;
    float4 a0 = make_float4(0.f, 0.f, 0.f, 0.f);
    float4 a1 = make_float4(0.f, 0.f, 0.f, 0.f);

    int i = g;
    int2 ep = (i < cnt) ? epair[beg + i] : make_int2(0, 0);
    while (i < cnt) {
        const int inext = i + 8;
        int2 epn = (inext < cnt) ? epair[beg + inext] : make_int2(0, 0);
        const int s = ep.x;
        const float w = __int_as_float(ep.y);
        float sc = s_src[(size_t)s * 4 + hh] + sdst;
        sc = fmaxf(sc, 0.2f * sc);                       // leaky relu (log2 domain)
        const float p = __builtin_amdgcn_exp2f(sc) * w;
        const float4* hp = (const float4*)(hfeat + (size_t)s * 64 + sl * 8);
        const float4 h0 = hp[0];
        const float4 h1 = hp[1];
        den += p;
        a0.x = fmaf(p, h0.x, a0.x); a0.y = fmaf(p, h0.y, a0.y);
        a0.z = fmaf(p, h0.z, a0.z); a0.w = fmaf(p, h0.w, a0.w);
        a1.x = fmaf(p, h1.x, a1.x); a1.y = fmaf(p, h1.y, a1.y);
        a1.z = fmaf(p, h1.z, a1.z); a1.w = fmaf(p, h1.w, a1.w);
        ep = epn; i = inext;
    }

    // merge 8 subgroups (lane bits 3,4,5)
    #pragma unroll
    for (int off = 8; off <= 32; off <<= 1) {
        den  += __shfl_xor(den, off, 64);
        a0.x += __shfl_xor(a0.x, off, 64); a0.y += __shfl_xor(a0.y, off, 64);
        a0.z += __shfl_xor(a0.z, off, 64); a0.w += __shfl_xor(a0.w, off, 64);
        a1.x += __shfl_xor(a1.x, off, 64); a1.y += __shfl_xor(a1.y, off, 64);
        a1.z += __shfl_xor(a1.z, off, 64); a1.w += __shfl_xor(a1.w, off, 64);
    }

    const float inv = 1.f / (den + 1e-16f);
    if (!FINAL) {
        if (g == 0) {
            float4 v0, v1;
            v0.x = a0.x * inv; v0.x = v0.x > 0.f ? v0.x : expm1f(v0.x);
            v0.y = a0.y * inv; v0.y = v0.y > 0.f ? v0.y : expm1f(v0.y);
            v0.z = a0.z * inv; v0.z = v0.z > 0.f ? v0.z : expm1f(v0.z);
            v0.w = a0.w * inv; v0.w = v0.w > 0.f ? v0.w : expm1f(v0.w);
            v1.x = a1.x * inv; v1.x = v1.x > 0.f ? v1.x : expm1f(v1.x);
            v1.y = a1.y * inv; v1.y = v1.y > 0.f ? v1.y : expm1f(v1.y);
            v1.z = a1.z * inv; v1.z = v1.z > 0.f ? v1.z : expm1f(v1.z);
            v1.w = a1.w * inv; v1.w = v1.w > 0.f ? v1.w : expm1f(v1.w);
            float4* op = (float4*)(outp + (size_t)n * 64 + sl * 8);
            op[0] = v0; op[1] = v1;
        }
    } else {
        const float4* wp = (const float4*)(whead + sl * 8);
        const float4 w0 = wp[0], w1 = wp[1];
        float v = (a0.x * w0.x + a0.y * w0.y + a0.z * w0.z + a0.w * w0.w
                 + a1.x * w1.x + a1.y * w1.y + a1.z * w1.z + a1.w * w1.w) * inv;
        #pragma unroll
        for (int off = 1; off <= 4; off <<= 1) v += __shfl_xor(v, off, 64);
        if (lane == 0) outp[n] = v + bhead[0];
    }
}

extern "C" void kernel_launch(void* const* d_in, const int* in_sizes, int n_in,
                              void* d_out, int out_size, void* d_ws, size_t ws_size,
                              hipStream_t stream) {
    const float* x      = (const float*)d_in[0];
    const int*   eidx   = (const int*)d_in[1];
    const float* ew     = (const float*)d_in[2];
    const float* tim    = (const float*)d_in[3];
    const float* omega0 = (const float*)d_in[4];
    const float* phase0 = (const float*)d_in[5];
    const float* W0     = (const float*)d_in[6];
    const float* asrc0  = (const float*)d_in[7];
    const float* adst0  = (const float*)d_in[8];
    const float* omega1 = (const float*)d_in[9];
    const float* phase1 = (const float*)d_in[10];
    const float* W1     = (const float*)d_in[11];
    const float* asrc1  = (const float*)d_in[12];
    const float* adst1  = (const float*)d_in[13];
    const float* Whead  = (const float*)d_in[14];
    const float* bhead  = (const float*)d_in[15];
    float* out = (float*)d_out;

    const int* src = eidx;
    const int* dst = eidx + N_EDGES;

    float* ws = (float*)d_ws;
    float* hfeat = ws;                               // N*64
    float* x1    = hfeat + (size_t)N_NODES * 64;     // N*64
    float* s_src = x1    + (size_t)N_NODES * 64;     // N*4
    float* s_dst = s_src + (size_t)N_NODES * 4;      // N*4
    int2* epair  = (int2*)(s_dst + (size_t)N_NODES * 4);   // E (8B each)
    int* deg     = (int*)(epair + (size_t)N_EDGES);  // N
    int* rowptr  = deg + N_NODES;                    // N
    int* bsum    = rowptr + N_NODES;                 // 256
    int* rank    = (int*)x1;                         // E ints, aliases x1 (dead until aggregate<0>)

    const int tf_grid   = (N_NODES + 63) / 64;       // 782
    const int agg_grid  = (N_NODES + 3) / 4;
    const int sc_grid   = ((N_EDGES + SC_CHUNK - 1) / SC_CHUNK) * NSEG;

    // ---- CSR build (edge structure shared by both layers) ----
    hipMemsetAsync(deg, 0, N_NODES * sizeof(int), stream);
    hist_kernel<<<sc_grid, 256, 0, stream>>>(dst, deg, rank);
    scanA_kernel<<<NB_SCAN, 256, 0, stream>>>(deg, bsum);
    scanB_kernel<<<1, 256, 0, stream>>>(bsum);
    scanC_kernel<<<NB_SCAN, 256, 0, stream>>>(deg, bsum, rowptr);
    scatter_kernel<<<sc_grid, 256, 0, stream>>>(dst, src, ew, rank, rowptr, epair);

    // ---- layer 0 ----
    transform_kernel<128><<<tf_grid, 256, 0, stream>>>(
        x, tim, omega0, phase0, W0, asrc0, adst0, hfeat, s_src, s_dst);
    aggregate_kernel<0><<<agg_grid, 256, 0, stream>>>(
        rowptr, deg, epair, s_src, s_dst, hfeat, Whead, bhead, x1);

    // ---- layer 1 (+ fused linear head) ----
    transform_kernel<64><<<tf_grid, 256, 0, stream>>>(
        x1, tim, omega1, phase1, W1, asrc1, adst1, hfeat, s_src, s_dst);
    aggregate_kernel<1><<<agg_grid, 256, 0, stream>>>(
        rowptr, deg, epair, s_src, s_dst, hfeat, Whead, bhead, out);
}